// Round 10
// baseline (142.639 us; speedup 1.0000x reference)
//
#include <hip/hip_runtime.h>
#include <hip/hip_bf16.h>
#include <math.h>

// Fused attention-gate, round 10: global_load_lds fp32 staging.
//   g = BN(in_g @ Wg); x = BN(in_x @ Wx); s = relu(g+x)
//   psi = sigmoid(BN(s @ Wp)); out = x * psi
// C'[f][px] = W^T . pix^T. W held in VGPR/AGPR (full K=256, both tensors).
// Pixels: HBM -> LDS via global_load_lds (16B DMA, zero VGPR, zero ds_write,
// no mid-tile vmcnt(0)). fp32 in LDS, ring-2; bf16 convert at fragment load.
// Swizzle: 32B-unit ^= px&7, applied as pre-swizzled per-lane GLOBAL source
// (DMA dest must stay linear) + swizzled ds_read address.

typedef __bf16 bf16x8 __attribute__((ext_vector_type(8)));
typedef float f32x4 __attribute__((ext_vector_type(4)));

#define GLOAD_LDS16(gp, lp)                                        \
  __builtin_amdgcn_global_load_lds(                                \
      (const __attribute__((address_space(1))) void*)(gp),         \
      (__attribute__((address_space(3))) void*)(lp), 16, 0, 0)

// lgkm-drain + barrier (no vmcnt drain): for LDS-only dependencies
#define BARRIER_LGKM() do {                                        \
    asm volatile("s_waitcnt lgkmcnt(0)" ::: "memory");             \
    __builtin_amdgcn_s_barrier();                                  \
    asm volatile("" ::: "memory");                                 \
  } while (0)

__device__ __forceinline__ unsigned short f2bf(float f) {
  union { float f; unsigned u; } v; v.f = f;
  unsigned r = (v.u + 0x7fffu + ((v.u >> 16) & 1u)) >> 16;
  return (unsigned short)r;
}

__device__ __forceinline__ bf16x8 cvt8f(f32x4 a, f32x4 b) {
  bf16x8 r;
  r[0]=(__bf16)a[0]; r[1]=(__bf16)a[1]; r[2]=(__bf16)a[2]; r[3]=(__bf16)a[3];
  r[4]=(__bf16)b[0]; r[5]=(__bf16)b[1]; r[6]=(__bf16)b[2]; r[7]=(__bf16)b[3];
  return r;
}

// ---------------- pre-kernel: fold BN into weights, fragment-linear ----------------
// Wfrag layout: [ftile(8)][ksg(8)][lane(64)][slot(8)] bf16 (64KB per tensor)
// lane l of fragment (ftile,ksg) holds W'[f=ftile*16+(l&15)][k=ksg*32+(l>>4)*8+slot]
__global__ __launch_bounds__(256) void fold_weights(
    const float* __restrict__ Wg, const float* __restrict__ bg,
    const float* __restrict__ gg, const float* __restrict__ beg,
    const float* __restrict__ mg, const float* __restrict__ vg,
    const float* __restrict__ Wx, const float* __restrict__ bx,
    const float* __restrict__ gx, const float* __restrict__ bex,
    const float* __restrict__ mx, const float* __restrict__ vx,
    const float* __restrict__ Wp, const float* __restrict__ bp,
    const float* __restrict__ gp, const float* __restrict__ bep,
    const float* __restrict__ mp, const float* __restrict__ vp,
    unsigned short* __restrict__ Bfg, unsigned short* __restrict__ Bfx,
    float* __restrict__ cg, float* __restrict__ cx,
    float* __restrict__ wps, float* __restrict__ cps) {
  int idx = blockIdx.x * 256 + threadIdx.x;  // 0..32767 = 256(c) * 128(f)
  int c = idx >> 7;    // Cin / k index
  int f = idx & 127;   // F index
  float ivg = gg[f] * rsqrtf(vg[f] + 1e-3f);
  float ivx = gx[f] * rsqrtf(vx[f] + 1e-3f);
  int ftile = f >> 4;
  int ksg = c >> 5;
  int lane = (((c >> 3) & 3) << 4) | (f & 15);
  int slot = c & 7;
  int off = ((ftile * 8 + ksg) * 64 + lane) * 8 + slot;
  Bfg[off] = f2bf(Wg[c * 128 + f] * ivg);
  Bfx[off] = f2bf(Wx[c * 128 + f] * ivx);
  if (idx < 128) {
    float ivg2 = gg[idx] * rsqrtf(vg[idx] + 1e-3f);
    float ivx2 = gx[idx] * rsqrtf(vx[idx] + 1e-3f);
    cg[idx] = bg[idx] * ivg2 + beg[idx] - mg[idx] * ivg2;
    cx[idx] = bx[idx] * ivx2 + bex[idx] - mx[idx] * ivx2;
    float ip = gp[0] * rsqrtf(vp[0] + 1e-3f);
    wps[idx] = Wp[idx] * ip;
    if (idx == 0) cps[0] = bp[0] * ip + bep[0] - mp[0] * ip;
  }
}

// ---------------- main fused kernel ----------------
// 512 threads = 8 waves; wave wid owns f-tile wid (16 f), W in registers.
// Each block: 8 consecutive 16-pixel tiles.
__global__ __launch_bounds__(512, 4) void attn_gate_main(
    const float* __restrict__ ing, const float* __restrict__ inx,
    const unsigned short* __restrict__ Wfg, const unsigned short* __restrict__ Wfx,
    const float* __restrict__ cgp, const float* __restrict__ cxp,
    const float* __restrict__ wpp, const float* __restrict__ cpp,
    float* __restrict__ out) {
  __shared__ __align__(16) float pixL[2][2][16][256];  // [buf][ten][px][k] fp32 64KB
  __shared__ __align__(16) float xT[2048];             // [16px*128f] swizzled   8KB
  __shared__ float psum[8][17];                        // [wave][px(+pad)]     544B

  const int tid = threadIdx.x;
  const int lane = tid & 63;
  const int wid = tid >> 6;        // f-tile of this wave
  const int l15 = lane & 15, l4 = lane >> 4;

  // ---- W fragments into registers (L2/L3-hot table) ----
  bf16x8 wfg[8], wfx[8];
  #pragma unroll
  for (int ksg = 0; ksg < 8; ++ksg) {
    const int off = ((wid * 8 + ksg) * 64 + lane) * 8;
    wfg[ksg] = *reinterpret_cast<const bf16x8*>(Wfg + off);
    wfx[ksg] = *reinterpret_cast<const bf16x8*>(Wfx + off);
  }
  const int fb = wid * 16 + l4 * 4;  // this lane's 4 consecutive f = fb+reg
  const f32x4 cgv = *reinterpret_cast<const f32x4*>(cgp + fb);
  const f32x4 cxv = *reinterpret_cast<const f32x4*>(cxp + fb);
  const f32x4 wpv = *reinterpret_cast<const f32x4*>(wpp + fb);
  const float cpsv = cpp[0];

  const long tile0 = (long)blockIdx.x * 8;

  // ---- staging: wave wid DMAs rows 4*wid..4*wid+3 (16 px x 2 tensors = 32 rows
  // of 1KB). Per row: lane loads 16B from PRE-SWIZZLED global slot, DMA writes
  // LDS linearly -> LDS slot s holds global slot s ^ ((px&7)<<1).
  auto stage = [&](int tt, int bb) {
    #pragma unroll
    for (int j = 0; j < 4; ++j) {
      const int r = wid * 4 + j;
      const int px = r & 15, ten = r >> 4;
      const float* src = ten ? inx : ing;
      const float* gp = src + ((tile0 + tt) * 16 + px) * 256
                        + ((lane ^ ((px & 7) << 1)) << 2);
      GLOAD_LDS16(gp, &pixL[bb][ten][px][0]);
    }
  };

  // staging-geometry constants for the store phase
  const int spx = tid >> 5;          // 0..15
  const int sk = tid & 31;           // 16B slot in 512B f32 row
  const int swoff = (spx << 9) | ((sk ^ (spx & 7)) << 4);  // xT byte offset

  // ---- prologue: DMA tile 0, wait (pipeline fill) ----
  stage(0, 0);
  __syncthreads();

  #pragma unroll
  for (int t = 0; t < 8; ++t) {
    const int buf = t & 1;
    // [1] DMA tile t+1 into buf^1 (zero registers; drains only at [4])
    if (t < 7) stage(t + 1, buf ^ 1);

    // [2] compute: 32 ds_read_b128 (fp32) + cvt + 16 MFMA
    f32x4 accg = {0.f, 0.f, 0.f, 0.f}, accx = {0.f, 0.f, 0.f, 0.f};
    #pragma unroll
    for (int ksg = 0; ksg < 8; ++ksg) {
      const int u = (ksg << 2) | l4;                       // 32B unit in row
      const int ra = (l15 << 10) | ((u ^ (l15 & 7)) << 5); // swizzled byte
      const char* pg = (const char*)&pixL[buf][0][0][0] + ra;
      const char* pxp = (const char*)&pixL[buf][1][0][0] + ra;
      f32x4 g0 = *(const f32x4*)pg,  g1 = *(const f32x4*)(pg + 16);
      f32x4 x0 = *(const f32x4*)pxp, x1 = *(const f32x4*)(pxp + 16);
      bf16x8 ag = cvt8f(g0, g1);
      bf16x8 ax = cvt8f(x0, x1);
      accg = __builtin_amdgcn_mfma_f32_16x16x32_bf16(wfg[ksg], ag, accg, 0, 0, 0);
      accx = __builtin_amdgcn_mfma_f32_16x16x32_bf16(wfx[ksg], ax, accx, 0, 0, 0);
    }

    // [3] epilogue: bias, relu(g+x), psi partials, xT write (swizzled)
    // C/D layout: px = lane&15, f = fb + reg
    f32x4 xv;
    float part = 0.f;
    #pragma unroll
    for (int reg = 0; reg < 4; ++reg) {
      float gv = accg[reg] + cgv[reg];
      xv[reg] = accx[reg] + cxv[reg];
      float s = gv + xv[reg];
      s = s > 0.f ? s : 0.f;
      part += s * wpv[reg];
    }
    part += __shfl_xor(part, 16);   // sum over the 4 l4-groups (16 f of wave)
    part += __shfl_xor(part, 32);
    if (lane < 16) psum[wid][lane] = part;
    const int xoff = (l15 << 9) | ((((wid << 2) | l4) ^ (l15 & 7)) << 4);
    *reinterpret_cast<f32x4*>((char*)xT + xoff) = xv;

    // [4] full barrier: publishes xT/psum; drains tile-t+1 DMA (issued ~one
    //     compute-phase ago -> near-zero stall) and the PREVIOUS tile's store
    __syncthreads();

    // [5] psi + coalesced store (512B full rows per wave)
    {
      float z = cpsv;
      #pragma unroll
      for (int w = 0; w < 8; ++w) z += psum[w][spx];
      const float psi = 1.f / (1.f + __expf(-z));
      f32x4 xr = *reinterpret_cast<const f32x4*>((const char*)xT + swoff);
      xr[0] *= psi; xr[1] *= psi; xr[2] *= psi; xr[3] *= psi;
      *reinterpret_cast<f32x4*>(out + ((tile0 + t) * 16 + spx) * 128 + sk * 4) = xr;
    }

    // [6] lgkm-only barrier: xT consumed, next tile may overwrite.
    //     Crucially does NOT drain the store just issued in [5].
    if (t < 7) BARRIER_LGKM();
  }
}

extern "C" void kernel_launch(void* const* d_in, const int* in_sizes, int n_in,
                              void* d_out, int out_size, void* d_ws, size_t ws_size,
                              hipStream_t stream) {
  const float* ing = (const float*)d_in[0];
  const float* inx = (const float*)d_in[1];
  char* ws = (char*)d_ws;
  unsigned short* Bfg = (unsigned short*)ws;                 // 64 KB
  unsigned short* Bfx = (unsigned short*)(ws + 65536);       // 64 KB
  float* cg  = (float*)(ws + 131072);                        // 512 B
  float* cx  = (float*)(ws + 131584);                        // 512 B
  float* wps = (float*)(ws + 132096);                        // 512 B
  float* cps = (float*)(ws + 132608);                        // 4 B

  fold_weights<<<128, 256, 0, stream>>>(
      (const float*)d_in[2],  (const float*)d_in[3],  (const float*)d_in[4],
      (const float*)d_in[5],  (const float*)d_in[6],  (const float*)d_in[7],
      (const float*)d_in[8],  (const float*)d_in[9],  (const float*)d_in[10],
      (const float*)d_in[11], (const float*)d_in[12], (const float*)d_in[13],
      (const float*)d_in[14], (const float*)d_in[15], (const float*)d_in[16],
      (const float*)d_in[17], (const float*)d_in[18], (const float*)d_in[19],
      Bfg, Bfx, cg, cx, wps, cps);

  const int npix = in_sizes[0] / 256;   // 131072
  const int ntiles = npix / 16;         // 8192
  attn_gate_main<<<ntiles / 8, 512, 0, stream>>>(
      ing, inx, Bfg, Bfx, cg, cx, wps, cps, (float*)d_out);
}

// Round 11
// 80.852 us; speedup vs baseline: 1.7642x; 1.7642x over previous
//
#include <hip/hip_runtime.h>
#include <hip/hip_bf16.h>
#include <math.h>

// Fused attention-gate, round 11: r4 structure + ONE barrier per tile.
//   g = BN(in_g @ Wg); x = BN(in_x @ Wx); s = relu(g+x)
//   psi = sigmoid(BN(s @ Wp)); out = x * psi
// C'[f][px] = W^T . pix^T. W held in VGPR/AGPR (full K=256, both tensors).
// Pixels reg-staged (fp32 global -> bf16 LDS, r4-proven swizzle), 16-px
// tiles, double-buffered, 4 tiles/block, 2048 blocks. xT/psum planes are
// ALSO double-buffered so the tile loop needs only one __syncthreads:
// overwrite of xT[buf] at t+2 is fenced from the store-read at t by the
// barrier at t+1. Coalesced 512B/wave output stores (no RMW).

typedef __bf16 bf16x8 __attribute__((ext_vector_type(8)));
typedef float f32x4 __attribute__((ext_vector_type(4)));

__device__ __forceinline__ unsigned short f2bf(float f) {
  union { float f; unsigned u; } v; v.f = f;
  unsigned r = (v.u + 0x7fffu + ((v.u >> 16) & 1u)) >> 16;
  return (unsigned short)r;
}

__device__ __forceinline__ bf16x8 cvt8(float4 a, float4 b) {
  bf16x8 r;
  r[0]=(__bf16)a.x; r[1]=(__bf16)a.y; r[2]=(__bf16)a.z; r[3]=(__bf16)a.w;
  r[4]=(__bf16)b.x; r[5]=(__bf16)b.y; r[6]=(__bf16)b.z; r[7]=(__bf16)b.w;
  return r;
}

// ---------------- pre-kernel: fold BN into weights, fragment-linear ----------------
// Wfrag layout: [ftile(8)][ksg(8)][lane(64)][slot(8)] bf16 (64KB per tensor)
// lane l of fragment (ftile,ksg) holds W'[f=ftile*16+(l&15)][k=ksg*32+(l>>4)*8+slot]
__global__ __launch_bounds__(256) void fold_weights(
    const float* __restrict__ Wg, const float* __restrict__ bg,
    const float* __restrict__ gg, const float* __restrict__ beg,
    const float* __restrict__ mg, const float* __restrict__ vg,
    const float* __restrict__ Wx, const float* __restrict__ bx,
    const float* __restrict__ gx, const float* __restrict__ bex,
    const float* __restrict__ mx, const float* __restrict__ vx,
    const float* __restrict__ Wp, const float* __restrict__ bp,
    const float* __restrict__ gp, const float* __restrict__ bep,
    const float* __restrict__ mp, const float* __restrict__ vp,
    unsigned short* __restrict__ Bfg, unsigned short* __restrict__ Bfx,
    float* __restrict__ cg, float* __restrict__ cx,
    float* __restrict__ wps, float* __restrict__ cps) {
  int idx = blockIdx.x * 256 + threadIdx.x;  // 0..32767 = 256(c) * 128(f)
  int c = idx >> 7;    // Cin / k index
  int f = idx & 127;   // F index
  float ivg = gg[f] * rsqrtf(vg[f] + 1e-3f);
  float ivx = gx[f] * rsqrtf(vx[f] + 1e-3f);
  int ftile = f >> 4;
  int ksg = c >> 5;
  int lane = (((c >> 3) & 3) << 4) | (f & 15);
  int slot = c & 7;
  int off = ((ftile * 8 + ksg) * 64 + lane) * 8 + slot;
  Bfg[off] = f2bf(Wg[c * 128 + f] * ivg);
  Bfx[off] = f2bf(Wx[c * 128 + f] * ivx);
  if (idx < 128) {
    float ivg2 = gg[idx] * rsqrtf(vg[idx] + 1e-3f);
    float ivx2 = gx[idx] * rsqrtf(vx[idx] + 1e-3f);
    cg[idx] = bg[idx] * ivg2 + beg[idx] - mg[idx] * ivg2;
    cx[idx] = bx[idx] * ivx2 + bex[idx] - mx[idx] * ivx2;
    float ip = gp[0] * rsqrtf(vp[0] + 1e-3f);
    wps[idx] = Wp[idx] * ip;
    if (idx == 0) cps[0] = bp[0] * ip + bep[0] - mp[0] * ip;
  }
}

// ---------------- main fused kernel ----------------
// 512 threads = 8 waves; wave wid owns f-tile wid (16 f), W in registers.
// Each block: 4 consecutive 16-pixel tiles, ONE barrier per tile.
__global__ __launch_bounds__(512, 4) void attn_gate_main(
    const float* __restrict__ ing, const float* __restrict__ inx,
    const unsigned short* __restrict__ Wfg, const unsigned short* __restrict__ Wfx,
    const float* __restrict__ cgp, const float* __restrict__ cxp,
    const float* __restrict__ wpp, const float* __restrict__ cpp,
    float* __restrict__ out) {
  __shared__ __align__(16) short pixT[2][2][4096];   // [buf][tensor][16px*256k] 32KB
  __shared__ __align__(16) float xT[2][2048];         // [buf][16px*128f] swz    16KB
  __shared__ __align__(16) float psum[2][16][8];      // [buf][px][wave]          1KB

  const int tid = threadIdx.x;
  const int lane = tid & 63;
  const int wid = tid >> 6;        // f-tile of this wave
  const int l15 = lane & 15, l4 = lane >> 4;

  // ---- W fragments into registers (L2/L3-hot table) ----
  bf16x8 wfg[8], wfx[8];
  #pragma unroll
  for (int ksg = 0; ksg < 8; ++ksg) {
    const int off = ((wid * 8 + ksg) * 64 + lane) * 8;
    wfg[ksg] = *reinterpret_cast<const bf16x8*>(Wfg + off);
    wfx[ksg] = *reinterpret_cast<const bf16x8*>(Wfx + off);
  }
  const int fb = wid * 16 + l4 * 4;  // this lane's 4 consecutive f = fb+reg
  const f32x4 cgv = *reinterpret_cast<const f32x4*>(cgp + fb);
  const f32x4 cxv = *reinterpret_cast<const f32x4*>(cxp + fb);
  const f32x4 wpv = *reinterpret_cast<const f32x4*>(wpp + fb);
  const float cpsv = cpp[0];

  // staging geometry: thread covers (px = tid>>5, 16B-slot sk = tid&31)
  const int spx = tid >> 5;
  const int sk = tid & 31;
  // swizzle: 16B-slot ^= row&7  (byte bits 4-6) — r4-proven family
  const int swoff = (spx << 9) | ((sk ^ (spx & 7)) << 4);
  const long tile0 = (long)blockIdx.x * 4;
  const float* gsrc = ing + (tile0 * 16 + spx) * 256 + sk * 8;
  const float* xsrc = inx + (tile0 * 16 + spx) * 256 + sk * 8;

  // ---- prologue: stage tile 0 ----
  {
    float4 a0 = *reinterpret_cast<const float4*>(gsrc);
    float4 a1 = *reinterpret_cast<const float4*>(gsrc + 4);
    float4 b0 = *reinterpret_cast<const float4*>(xsrc);
    float4 b1 = *reinterpret_cast<const float4*>(xsrc + 4);
    *reinterpret_cast<bf16x8*>((char*)&pixT[0][0][0] + swoff) = cvt8(a0, a1);
    *reinterpret_cast<bf16x8*>((char*)&pixT[0][1][0] + swoff) = cvt8(b0, b1);
  }
  __syncthreads();

  #pragma unroll
  for (int t = 0; t < 4; ++t) {
    const int buf = t & 1;
    // [1] issue next tile's global loads (hidden under this tile's compute)
    float4 sg0, sg1, sx0, sx1;
    if (t < 3) {
      const float* g_ = gsrc + (t + 1) * 4096;
      const float* x_ = xsrc + (t + 1) * 4096;
      sg0 = *reinterpret_cast<const float4*>(g_);
      sg1 = *reinterpret_cast<const float4*>(g_ + 4);
      sx0 = *reinterpret_cast<const float4*>(x_);
      sx1 = *reinterpret_cast<const float4*>(x_ + 4);
    }

    // [2] compute: 16 ds_read + 16 MFMA, zero global loads
    f32x4 accg = {0.f, 0.f, 0.f, 0.f}, accx = {0.f, 0.f, 0.f, 0.f};
    #pragma unroll
    for (int ksg = 0; ksg < 8; ++ksg) {
      const int ra = (l15 << 9) | ((((ksg << 2) | l4) ^ (l15 & 7)) << 4);
      bf16x8 pg = *reinterpret_cast<const bf16x8*>((const char*)&pixT[buf][0][0] + ra);
      bf16x8 px = *reinterpret_cast<const bf16x8*>((const char*)&pixT[buf][1][0] + ra);
      accg = __builtin_amdgcn_mfma_f32_16x16x32_bf16(wfg[ksg], pg, accg, 0, 0, 0);
      accx = __builtin_amdgcn_mfma_f32_16x16x32_bf16(wfx[ksg], px, accx, 0, 0, 0);
    }

    // [3] epilogue: bias, relu(g+x), psi partials, xT write (all dbuf'd)
    // C/D layout: px = lane&15, f = fb + reg
    f32x4 xv;
    float part = 0.f;
    #pragma unroll
    for (int reg = 0; reg < 4; ++reg) {
      float gv = accg[reg] + cgv[reg];
      xv[reg] = accx[reg] + cxv[reg];
      float s = gv + xv[reg];
      s = s > 0.f ? s : 0.f;
      part += s * wpv[reg];
    }
    part += __shfl_xor(part, 16);   // sum over the 4 l4-groups (16 f of wave)
    part += __shfl_xor(part, 32);
    if (lane < 16) psum[buf][l15][wid] = part;
    const int xoff = (l15 << 9) | ((((wid << 2) | l4) ^ (l15 & 7)) << 4);
    *reinterpret_cast<f32x4*>((char*)&xT[buf][0] + xoff) = xv;

    // [4] write next tile's staged data into the other pixT buffer
    if (t < 3) {
      *reinterpret_cast<bf16x8*>((char*)&pixT[buf ^ 1][0][0] + swoff) = cvt8(sg0, sg1);
      *reinterpret_cast<bf16x8*>((char*)&pixT[buf ^ 1][1][0] + swoff) = cvt8(sx0, sx1);
    }

    // [5] THE barrier: publishes xT/psum/pixT-next; xT[buf] overwrite at
    //     t+2 is fenced from this tile's store-read by the barrier at t+1.
    __syncthreads();

    // [6] psi + coalesced store (512B full rows per wave, exact lines)
    {
      const f32x4 pa = *reinterpret_cast<const f32x4*>(&psum[buf][spx][0]);
      const f32x4 pb = *reinterpret_cast<const f32x4*>(&psum[buf][spx][4]);
      const float z = pa[0] + pa[1] + pa[2] + pa[3]
                    + pb[0] + pb[1] + pb[2] + pb[3] + cpsv;
      const float psi = 1.f / (1.f + __expf(-z));
      f32x4 xr = *reinterpret_cast<const f32x4*>((const char*)&xT[buf][0] + swoff);
      xr[0] *= psi; xr[1] *= psi; xr[2] *= psi; xr[3] *= psi;
      *reinterpret_cast<f32x4*>(out + ((tile0 + t) * 16 + spx) * 128 + sk * 4) = xr;
    }
  }
}

extern "C" void kernel_launch(void* const* d_in, const int* in_sizes, int n_in,
                              void* d_out, int out_size, void* d_ws, size_t ws_size,
                              hipStream_t stream) {
  const float* ing = (const float*)d_in[0];
  const float* inx = (const float*)d_in[1];
  char* ws = (char*)d_ws;
  unsigned short* Bfg = (unsigned short*)ws;                 // 64 KB
  unsigned short* Bfx = (unsigned short*)(ws + 65536);       // 64 KB
  float* cg  = (float*)(ws + 131072);                        // 512 B
  float* cx  = (float*)(ws + 131584);                        // 512 B
  float* wps = (float*)(ws + 132096);                        // 512 B
  float* cps = (float*)(ws + 132608);                        // 4 B

  fold_weights<<<128, 256, 0, stream>>>(
      (const float*)d_in[2],  (const float*)d_in[3],  (const float*)d_in[4],
      (const float*)d_in[5],  (const float*)d_in[6],  (const float*)d_in[7],
      (const float*)d_in[8],  (const float*)d_in[9],  (const float*)d_in[10],
      (const float*)d_in[11], (const float*)d_in[12], (const float*)d_in[13],
      (const float*)d_in[14], (const float*)d_in[15], (const float*)d_in[16],
      (const float*)d_in[17], (const float*)d_in[18], (const float*)d_in[19],
      Bfg, Bfx, cg, cx, wps, cps);

  const int npix = in_sizes[0] / 256;   // 131072
  const int ntiles = npix / 16;         // 8192
  attn_gate_main<<<ntiles / 4, 512, 0, stream>>>(
      ing, inx, Bfg, Bfx, cg, cx, wps, cps, (float*)d_out);
}